// Round 1
// baseline (726.200 us; speedup 1.0000x reference)
//
#include <hip/hip_runtime.h>

// ---------------------------------------------------------------------------
// GAT_4733053960619: SAGEConv(mean) -> ELU -> GAT(2 heads,64) -> ELU -> GAT(1,47)
// N=50000, E=800000, IN_FEATS=256. All fp32.
//
// Plan:
//   y = x @ W_neigh, z = x @ W_self                     (GEMM, fp32)
//   CSR by dst (deg/scan/scatter, int atomics)
//   h0 = elu(z + segsum(y[src])/deg + b)                (wave/node gather)
//   feat1 = h0 @ gat1_w                                 (GEMM)
//   el1/er1 per node                                    (wave/node reduce)
//   h1 = elu(online-softmax-agg(feat1) + b1)            (wave/node, fused GAT)
//   feat2 = h1 @ gat2_w (ldc=48)                        (GEMM)
//   el2/er2 per node
//   out = softmax-agg(feat2) + b2                       (wave/node, fused GAT)
// ---------------------------------------------------------------------------

__device__ __forceinline__ float wave_sum(float v) {
#pragma unroll
  for (int o = 32; o > 0; o >>= 1) v += __shfl_xor(v, o, 64);
  return v;
}

__device__ __forceinline__ float elu_f(float v) {
  return v > 0.f ? v : expm1f(v);
}

// ---------------- CSR build ----------------
__global__ __launch_bounds__(256) void deg_kernel(const int* __restrict__ dst,
                                                  int* __restrict__ deg, int E) {
  int i = blockIdx.x * 256 + threadIdx.x;
  if (i < E) atomicAdd(&deg[dst[i]], 1);
}

__global__ __launch_bounds__(1024) void scan_kernel(const int* __restrict__ deg,
                                                    int* __restrict__ row_start, int n) {
  __shared__ int tmp[1024];
  __shared__ int s_carry;
  int t = threadIdx.x;
  if (t == 0) s_carry = 0;
  __syncthreads();
  for (int base = 0; base < n; base += 1024) {
    int v = (base + t < n) ? deg[base + t] : 0;
    tmp[t] = v;
    __syncthreads();
    for (int off = 1; off < 1024; off <<= 1) {
      int add = (t >= off) ? tmp[t - off] : 0;
      __syncthreads();
      tmp[t] += add;
      __syncthreads();
    }
    int incl = tmp[t];
    int carry = s_carry;  // read before update barrier
    if (base + t < n) row_start[base + t] = carry + incl - v;
    __syncthreads();
    if (t == 1023) s_carry = carry + incl;
    __syncthreads();
  }
  if (t == 0) row_start[n] = s_carry;
}

__global__ __launch_bounds__(256) void scatter_kernel(const int* __restrict__ src,
                                                      const int* __restrict__ dst,
                                                      const int* __restrict__ row_start,
                                                      int* __restrict__ cursor,
                                                      int* __restrict__ csr_src, int E) {
  int i = blockIdx.x * 256 + threadIdx.x;
  if (i < E) {
    int d = dst[i];
    int p = atomicAdd(&cursor[d], 1);
    csr_src[row_start[d] + p] = src[i];
  }
}

// ---------------- fp32 register-tiled GEMM ----------------
// C[M,N] = A[M,K] @ W[K,N]; optional bias + ELU epilogue.
template <int BM, int BN, int BK, int TM, int TN>
__global__ __launch_bounds__(256) void gemm_f32(const float* __restrict__ A, int lda,
                                                const float* __restrict__ W, int ldw,
                                                float* __restrict__ C, int ldc,
                                                int M, int N, int K,
                                                const float* __restrict__ bias, int do_elu) {
  constexpr int THREADS = (BM / TM) * (BN / TN);
  static_assert(THREADS == 256, "expect 256 threads");
  __shared__ float As[BK][BM + 4];
  __shared__ float Ws[BK][BN + 4];
  const int tid = threadIdx.x;
  const int tc = tid % (BN / TN);
  const int tr = tid / (BN / TN);
  const int row0 = blockIdx.x * BM;

  float acc[TM][TN] = {};
  for (int k0 = 0; k0 < K; k0 += BK) {
#pragma unroll
    for (int i = tid; i < BM * BK; i += THREADS) {
      int r = i / BK, kk = i % BK;
      int gr = row0 + r;
      As[kk][r] = (gr < M) ? A[(size_t)gr * lda + k0 + kk] : 0.f;
    }
#pragma unroll
    for (int i = tid; i < BK * BN; i += THREADS) {
      int kk = i / BN, c = i % BN;
      Ws[kk][c] = (c < N) ? W[(size_t)(k0 + kk) * ldw + c] : 0.f;
    }
    __syncthreads();
#pragma unroll
    for (int kk = 0; kk < BK; ++kk) {
      float a[TM], b[TN];
#pragma unroll
      for (int i = 0; i < TM; i++) a[i] = As[kk][tr * TM + i];
#pragma unroll
      for (int j = 0; j < TN; j++) b[j] = Ws[kk][tc * TN + j];
#pragma unroll
      for (int i = 0; i < TM; i++)
#pragma unroll
        for (int j = 0; j < TN; j++) acc[i][j] = fmaf(a[i], b[j], acc[i][j]);
    }
    __syncthreads();
  }
#pragma unroll
  for (int i = 0; i < TM; i++) {
    int gr = row0 + tr * TM + i;
    if (gr >= M) continue;
#pragma unroll
    for (int j = 0; j < TN; j++) {
      int gc = tc * TN + j;
      if (gc >= N) continue;
      float v = acc[i][j];
      if (bias) v += bias[gc];
      if (do_elu) v = elu_f(v);
      C[(size_t)gr * ldc + gc] = v;
    }
  }
}

// ---------------- SAGE aggregation (wave per node) ----------------
// h0 = elu(z + (sum_{u in N(n)} y[u]) / max(deg,1) + b)
__global__ __launch_bounds__(256) void sage_agg(const float* __restrict__ z,
                                                const float* __restrict__ y,
                                                const int* __restrict__ row_start,
                                                const int* __restrict__ csr_src,
                                                const float* __restrict__ b,
                                                float* __restrict__ h0, int N) {
  int wid = threadIdx.x >> 6;
  int lane = threadIdx.x & 63;
  int n = blockIdx.x * 4 + wid;
  if (n >= N) return;
  int s = row_start[n], e = row_start[n + 1];
  float a0 = 0.f, a1 = 0.f;
  for (int i = s; i < e; ++i) {
    const float* yr = y + (size_t)csr_src[i] * 128;
    a0 += yr[lane];
    a1 += yr[lane + 64];
  }
  float inv = 1.0f / fmaxf((float)(e - s), 1.0f);
  size_t base = (size_t)n * 128;
  float v0 = z[base + lane] + a0 * inv + b[lane];
  float v1 = z[base + 64 + lane] + a1 * inv + b[64 + lane];
  h0[base + lane] = elu_f(v0);
  h0[base + 64 + lane] = elu_f(v1);
}

// ---------------- per-node attention logits (layer 1: 2 heads x 64) --------
__global__ __launch_bounds__(256) void elr1_kernel(const float* __restrict__ feat,
                                                   const float* __restrict__ al,
                                                   const float* __restrict__ ar,
                                                   float* __restrict__ el,
                                                   float* __restrict__ er, int N) {
  int wid = threadIdx.x >> 6;
  int lane = threadIdx.x & 63;
  int n = blockIdx.x * 4 + wid;
  if (n >= N) return;
  size_t base = (size_t)n * 128;
  float f0 = feat[base + lane];
  float f1 = feat[base + 64 + lane];
  float e0 = wave_sum(f0 * al[lane]);
  float e1 = wave_sum(f1 * al[64 + lane]);
  float r0 = wave_sum(f0 * ar[lane]);
  float r1 = wave_sum(f1 * ar[64 + lane]);
  if (lane == 0) {
    el[n * 2] = e0;
    el[n * 2 + 1] = e1;
    er[n * 2] = r0;
    er[n * 2 + 1] = r1;
  }
}

// ---------------- fused GAT layer 1 aggregation (wave per node) ------------
__global__ __launch_bounds__(256) void gat1_agg(const float* __restrict__ feat,
                                                const float* __restrict__ el,
                                                const float* __restrict__ er,
                                                const int* __restrict__ row_start,
                                                const int* __restrict__ csr_src,
                                                const float* __restrict__ b,
                                                float* __restrict__ h1, int N) {
  int wid = threadIdx.x >> 6;
  int lane = threadIdx.x & 63;
  int n = blockIdx.x * 4 + wid;
  if (n >= N) return;
  float ern0 = er[n * 2], ern1 = er[n * 2 + 1];
  float m0 = -INFINITY, m1 = -INFINITY;
  float s0 = 0.f, s1 = 0.f, acc0 = 0.f, acc1 = 0.f;
  int beg = row_start[n], end = row_start[n + 1];
  for (int i = beg; i < end; ++i) {
    int u = csr_src[i];
    float e0 = el[u * 2] + ern0;
    float e1 = el[u * 2 + 1] + ern1;
    e0 = e0 > 0.f ? e0 : 0.2f * e0;
    e1 = e1 > 0.f ? e1 : 0.2f * e1;
    const float* fr = feat + (size_t)u * 128;
    float mn0 = fmaxf(m0, e0);
    float sc0 = expf(m0 - mn0);
    float p0 = expf(e0 - mn0);
    s0 = s0 * sc0 + p0;
    acc0 = acc0 * sc0 + p0 * fr[lane];
    m0 = mn0;
    float mn1 = fmaxf(m1, e1);
    float sc1 = expf(m1 - mn1);
    float p1 = expf(e1 - mn1);
    s1 = s1 * sc1 + p1;
    acc1 = acc1 * sc1 + p1 * fr[64 + lane];
    m1 = mn1;
  }
  float o0 = acc0 / fmaxf(s0, 1e-9f) + b[lane];
  float o1 = acc1 / fmaxf(s1, 1e-9f) + b[64 + lane];
  size_t base = (size_t)n * 128;
  h1[base + lane] = elu_f(o0);
  h1[base + 64 + lane] = elu_f(o1);
}

// ---------------- per-node attention logits (layer 2: 1 head x 47) --------
__global__ __launch_bounds__(256) void elr2_kernel(const float* __restrict__ feat,  // ld 48
                                                   const float* __restrict__ al,
                                                   const float* __restrict__ ar,
                                                   float* __restrict__ el,
                                                   float* __restrict__ er, int N) {
  int wid = threadIdx.x >> 6;
  int lane = threadIdx.x & 63;
  int n = blockIdx.x * 4 + wid;
  if (n >= N) return;
  float f = 0.f, a = 0.f, r = 0.f;
  if (lane < 47) {
    f = feat[(size_t)n * 48 + lane];
    a = al[lane];
    r = ar[lane];
  }
  float e = wave_sum(f * a);
  float rr = wave_sum(f * r);
  if (lane == 0) {
    el[n] = e;
    er[n] = rr;
  }
}

// ---------------- fused GAT layer 2 aggregation -> d_out ------------------
__global__ __launch_bounds__(256) void gat2_agg(const float* __restrict__ feat,  // ld 48
                                                const float* __restrict__ el,
                                                const float* __restrict__ er,
                                                const int* __restrict__ row_start,
                                                const int* __restrict__ csr_src,
                                                const float* __restrict__ b,
                                                float* __restrict__ out, int N) {
  int wid = threadIdx.x >> 6;
  int lane = threadIdx.x & 63;
  int n = blockIdx.x * 4 + wid;
  if (n >= N) return;
  float ern = er[n];
  float m = -INFINITY, s = 0.f, acc = 0.f;
  int beg = row_start[n], end = row_start[n + 1];
  int lidx = lane < 47 ? lane : 0;
  for (int i = beg; i < end; ++i) {
    int u = csr_src[i];
    float e = el[u] + ern;
    e = e > 0.f ? e : 0.2f * e;
    float mn = fmaxf(m, e);
    float sc = expf(m - mn);
    float p = expf(e - mn);
    s = s * sc + p;
    acc = acc * sc + p * feat[(size_t)u * 48 + lidx];
    m = mn;
  }
  if (lane < 47) {
    out[(size_t)n * 47 + lane] = acc / fmaxf(s, 1e-9f) + b[lane];
  }
}

// ---------------------------------------------------------------------------
extern "C" void kernel_launch(void* const* d_in, const int* in_sizes, int n_in,
                              void* d_out, int out_size, void* d_ws, size_t ws_size,
                              hipStream_t stream) {
  const float* x = (const float*)d_in[0];
  const int* src = (const int*)d_in[1];
  const int* dst = (const int*)d_in[2];
  const float* sage_w_self = (const float*)d_in[3];
  const float* sage_w_neigh = (const float*)d_in[4];
  const float* sage_b = (const float*)d_in[5];
  const float* gat1_w = (const float*)d_in[6];
  const float* gat1_al = (const float*)d_in[7];
  const float* gat1_ar = (const float*)d_in[8];
  const float* gat1_b = (const float*)d_in[9];
  const float* gat2_w = (const float*)d_in[10];
  const float* gat2_al = (const float*)d_in[11];
  const float* gat2_ar = (const float*)d_in[12];
  const float* gat2_b = (const float*)d_in[13];
  float* out = (float*)d_out;

  const int N = in_sizes[0] / 256;
  const int E = in_sizes[1];

  char* ws = (char*)d_ws;
  size_t off = 0;
  auto alloc = [&](size_t bytes) {
    size_t o = off;
    off += (bytes + 255) & ~(size_t)255;
    return o;
  };
  int* deg_i = (int*)(ws + alloc((size_t)N * 4));
  int* row_start = (int*)(ws + alloc((size_t)(N + 1) * 4));
  int* cursor = (int*)(ws + alloc((size_t)N * 4));
  int* csr_src = (int*)(ws + alloc((size_t)E * 4));
  float* bufA = (float*)(ws + alloc((size_t)N * 128 * 4));  // z -> feat1
  float* bufB = (float*)(ws + alloc((size_t)N * 128 * 4));  // y -> h1
  float* bufC = (float*)(ws + alloc((size_t)N * 128 * 4));  // h0 -> feat2(ld48)
  float* el1 = (float*)(ws + alloc((size_t)N * 2 * 4));
  float* er1 = (float*)(ws + alloc((size_t)N * 2 * 4));
  float* el2 = (float*)(ws + alloc((size_t)N * 4));
  float* er2 = (float*)(ws + alloc((size_t)N * 4));
  (void)ws_size;
  (void)n_in;
  (void)out_size;

  float* z = bufA;
  float* y = bufB;
  float* h0 = bufC;
  float* feat1 = bufA;  // z dead after sage_agg
  float* h1 = bufB;     // y dead after sage_agg
  float* feat2 = bufC;  // h0 dead after gat1 gemm

  hipMemsetAsync(deg_i, 0, (size_t)N * 4, stream);
  hipMemsetAsync(cursor, 0, (size_t)N * 4, stream);

  const int eb = (E + 255) / 256;
  const int nb4 = (N + 3) / 4;
  const int gb = (N + 63) / 64;

  deg_kernel<<<eb, 256, 0, stream>>>(dst, deg_i, E);
  scan_kernel<<<1, 1024, 0, stream>>>(deg_i, row_start, N);
  scatter_kernel<<<eb, 256, 0, stream>>>(src, dst, row_start, cursor, csr_src, E);

  // layer 0 GEMMs: z = x @ W_self, y = x @ W_neigh
  gemm_f32<64, 128, 16, 4, 8><<<gb, 256, 0, stream>>>(x, 256, sage_w_self, 128, z, 128,
                                                      N, 128, 256, nullptr, 0);
  gemm_f32<64, 128, 16, 4, 8><<<gb, 256, 0, stream>>>(x, 256, sage_w_neigh, 128, y, 128,
                                                      N, 128, 256, nullptr, 0);
  sage_agg<<<nb4, 256, 0, stream>>>(z, y, row_start, csr_src, sage_b, h0, N);

  // GAT layer 1
  gemm_f32<64, 128, 16, 4, 8><<<gb, 256, 0, stream>>>(h0, 128, gat1_w, 128, feat1, 128,
                                                      N, 128, 128, nullptr, 0);
  elr1_kernel<<<nb4, 256, 0, stream>>>(feat1, gat1_al, gat1_ar, el1, er1, N);
  gat1_agg<<<nb4, 256, 0, stream>>>(feat1, el1, er1, row_start, csr_src, gat1_b, h1, N);

  // GAT layer 2
  gemm_f32<64, 64, 16, 4, 4><<<gb, 256, 0, stream>>>(h1, 128, gat2_w, 47, feat2, 48,
                                                     N, 47, 128, nullptr, 0);
  elr2_kernel<<<nb4, 256, 0, stream>>>(feat2, gat2_al, gat2_ar, el2, er2, N);
  gat2_agg<<<nb4, 256, 0, stream>>>(feat2, el2, er2, row_start, csr_src, gat2_b, out, N);
}

// Round 2
// 612.987 us; speedup vs baseline: 1.1847x; 1.1847x over previous
//
#include <hip/hip_runtime.h>

// ---------------------------------------------------------------------------
// GAT_4733053960619: SAGEConv(mean) -> ELU -> GAT(2 heads,64) -> ELU -> GAT(1,47)
// N=50000, E=800000, IN_FEATS=256. All fp32.
//
// R1 restructure: softmax scalar work moved to thread-per-node attn kernels
// (computed once per edge, not replicated x64 lanes); aggregation kernels are
// pure gather-fma. feat1/y stored head-interleaved [N][64][2] so each lane
// gathers one float2 instead of two floats.
// ---------------------------------------------------------------------------

__device__ __forceinline__ float wave_sum(float v) {
#pragma unroll
  for (int o = 32; o > 0; o >>= 1) v += __shfl_xor(v, o, 64);
  return v;
}

__device__ __forceinline__ float elu_f(float v) {
  return v > 0.f ? v : __expf(v) - 1.0f;
}

// ---------------- CSR build ----------------
__global__ __launch_bounds__(256) void deg_kernel(const int* __restrict__ dst,
                                                  int* __restrict__ deg, int E) {
  int i = blockIdx.x * 256 + threadIdx.x;
  if (i < E) atomicAdd(&deg[dst[i]], 1);
}

// single-block scan, wave-shuffle based (few barriers)
__global__ __launch_bounds__(1024) void scan_kernel(const int* __restrict__ deg,
                                                    int* __restrict__ row_start, int n) {
  __shared__ int wsum[16];
  __shared__ int wpre[16];
  __shared__ int s_carry;
  const int t = threadIdx.x;
  const int lane = t & 63;
  const int w = t >> 6;
  if (t == 0) s_carry = 0;
  __syncthreads();
  for (int base = 0; base < n; base += 1024) {
    int v = (base + t < n) ? deg[base + t] : 0;
    int inc = v;
#pragma unroll
    for (int o = 1; o < 64; o <<= 1) {
      int u = __shfl_up(inc, o, 64);
      if (lane >= o) inc += u;
    }
    if (lane == 63) wsum[w] = inc;
    __syncthreads();
    if (w == 0 && lane < 16) {
      int s = wsum[lane];
      int p = s;
#pragma unroll
      for (int o = 1; o < 16; o <<= 1) {
        int u = __shfl_up(p, o, 64);
        if (lane >= o) p += u;
      }
      wpre[lane] = p - s;  // exclusive prefix of wave sums
    }
    __syncthreads();
    int carry = s_carry;
    if (base + t < n) row_start[base + t] = carry + wpre[w] + inc - v;
    __syncthreads();  // everyone read s_carry before update
    if (t == 1023) s_carry = carry + wpre[15] + inc;
    __syncthreads();
  }
  if (t == 0) row_start[n] = s_carry;
}

__global__ __launch_bounds__(256) void scatter_kernel(const int* __restrict__ src,
                                                      const int* __restrict__ dst,
                                                      const int* __restrict__ row_start,
                                                      int* __restrict__ cursor,
                                                      int* __restrict__ csr_src, int E) {
  int i = blockIdx.x * 256 + threadIdx.x;
  if (i < E) {
    int d = dst[i];
    int p = atomicAdd(&cursor[d], 1);
    csr_src[row_start[d] + p] = src[i];
  }
}

// ---------------- fp32 register-tiled GEMM ----------------
// C[M,N] = A[M,K] @ W[K,N]. If ILV: store logical col gc at (gc&63)*2+(gc>>6)
// (requires N==128): head-interleaved layout [M][64][2].
template <int BM, int BN, int BK, int TM, int TN, int ILV>
__global__ __launch_bounds__(256) void gemm_f32(const float* __restrict__ A, int lda,
                                                const float* __restrict__ W, int ldw,
                                                float* __restrict__ C, int ldc,
                                                int M, int N, int K) {
  constexpr int THREADS = (BM / TM) * (BN / TN);
  static_assert(THREADS == 256, "expect 256 threads");
  __shared__ float As[BK][BM + 4];
  __shared__ float Ws[BK][BN + 4];
  const int tid = threadIdx.x;
  const int tc = tid % (BN / TN);
  const int tr = tid / (BN / TN);
  const int row0 = blockIdx.x * BM;

  float acc[TM][TN] = {};
  for (int k0 = 0; k0 < K; k0 += BK) {
#pragma unroll
    for (int i = tid; i < BM * BK; i += THREADS) {
      int r = i / BK, kk = i % BK;
      int gr = row0 + r;
      As[kk][r] = (gr < M) ? A[(size_t)gr * lda + k0 + kk] : 0.f;
    }
#pragma unroll
    for (int i = tid; i < BK * BN; i += THREADS) {
      int kk = i / BN, c = i % BN;
      Ws[kk][c] = (c < N) ? W[(size_t)(k0 + kk) * ldw + c] : 0.f;
    }
    __syncthreads();
#pragma unroll
    for (int kk = 0; kk < BK; ++kk) {
      float a[TM], b[TN];
#pragma unroll
      for (int i = 0; i < TM; i++) a[i] = As[kk][tr * TM + i];
#pragma unroll
      for (int j = 0; j < TN; j++) b[j] = Ws[kk][tc * TN + j];
#pragma unroll
      for (int i = 0; i < TM; i++)
#pragma unroll
        for (int j = 0; j < TN; j++) acc[i][j] = fmaf(a[i], b[j], acc[i][j]);
    }
    __syncthreads();
  }
#pragma unroll
  for (int i = 0; i < TM; i++) {
    int gr = row0 + tr * TM + i;
    if (gr >= M) continue;
#pragma unroll
    for (int j = 0; j < TN; j++) {
      int gc = tc * TN + j;
      if (gc >= N) continue;
      int oc = ILV ? ((gc & 63) * 2 + (gc >> 6)) : gc;
      C[(size_t)gr * ldc + oc] = acc[i][j];
    }
  }
}

// ---------------- SAGE aggregation (wave per node) ----------------
// h0 = elu(z + (sum y[u]) / max(deg,1) + b); y is interleaved [N][64][2]
__global__ __launch_bounds__(256) void sage_agg(const float* __restrict__ z,
                                                const float2* __restrict__ yI,
                                                const int* __restrict__ row_start,
                                                const int* __restrict__ csr_src,
                                                const float* __restrict__ b,
                                                float* __restrict__ h0, int N) {
  int wid = threadIdx.x >> 6;
  int lane = threadIdx.x & 63;
  int n = blockIdx.x * 4 + wid;
  if (n >= N) return;
  int s = row_start[n], e = row_start[n + 1];
  float a0 = 0.f, a1 = 0.f;
  int i = s;
  for (; i + 1 < e; i += 2) {
    int u0 = csr_src[i], u1 = csr_src[i + 1];
    float2 f0 = yI[(size_t)u0 * 64 + lane];
    float2 f1 = yI[(size_t)u1 * 64 + lane];
    a0 += f0.x + f1.x;
    a1 += f0.y + f1.y;
  }
  if (i < e) {
    float2 f = yI[(size_t)csr_src[i] * 64 + lane];
    a0 += f.x;
    a1 += f.y;
  }
  float inv = 1.0f / fmaxf((float)(e - s), 1.0f);
  size_t base = (size_t)n * 128;
  float v0 = z[base + lane] + a0 * inv + b[lane];
  float v1 = z[base + 64 + lane] + a1 * inv + b[64 + lane];
  h0[base + lane] = elu_f(v0);
  h0[base + 64 + lane] = elu_f(v1);
}

// ---------------- per-node attention logits (layer 1) ----------------------
// feat interleaved [N][64][2]; el/er stored as float2 per node
__global__ __launch_bounds__(256) void elr1_kernel(const float2* __restrict__ featI,
                                                   const float* __restrict__ al,
                                                   const float* __restrict__ ar,
                                                   float2* __restrict__ el,
                                                   float2* __restrict__ er, int N) {
  int wid = threadIdx.x >> 6;
  int lane = threadIdx.x & 63;
  int n = blockIdx.x * 4 + wid;
  if (n >= N) return;
  float2 f = featI[(size_t)n * 64 + lane];
  float e0 = wave_sum(f.x * al[lane]);
  float e1 = wave_sum(f.y * al[64 + lane]);
  float r0 = wave_sum(f.x * ar[lane]);
  float r1 = wave_sum(f.y * ar[64 + lane]);
  if (lane == 0) {
    el[n] = make_float2(e0, e1);
    er[n] = make_float2(r0, r1);
  }
}

// ---------------- attn1: thread per node, unnormalized softmax weights -----
__global__ __launch_bounds__(256) void attn1_kernel(const float2* __restrict__ el,
                                                    const float2* __restrict__ er,
                                                    const int* __restrict__ row_start,
                                                    const int* __restrict__ csr_src,
                                                    float2* __restrict__ alpha,
                                                    float2* __restrict__ inv_s, int N) {
  int n = blockIdx.x * 256 + threadIdx.x;
  if (n >= N) return;
  int beg = row_start[n], end = row_start[n + 1];
  float2 r = er[n];
  float m0 = -INFINITY, m1 = -INFINITY;
  for (int i = beg; i < end; ++i) {
    float2 l = el[csr_src[i]];
    float e0 = l.x + r.x;
    e0 = e0 > 0.f ? e0 : 0.2f * e0;
    float e1 = l.y + r.y;
    e1 = e1 > 0.f ? e1 : 0.2f * e1;
    m0 = fmaxf(m0, e0);
    m1 = fmaxf(m1, e1);
  }
  float s0 = 0.f, s1 = 0.f;
  for (int i = beg; i < end; ++i) {
    float2 l = el[csr_src[i]];
    float e0 = l.x + r.x;
    e0 = e0 > 0.f ? e0 : 0.2f * e0;
    float e1 = l.y + r.y;
    e1 = e1 > 0.f ? e1 : 0.2f * e1;
    float p0 = __expf(e0 - m0);
    float p1 = __expf(e1 - m1);
    s0 += p0;
    s1 += p1;
    alpha[i] = make_float2(p0, p1);
  }
  inv_s[n] = make_float2(1.0f / fmaxf(s0, 1e-9f), 1.0f / fmaxf(s1, 1e-9f));
}

// ---------------- fused GAT layer 1 aggregation (wave per node) ------------
__global__ __launch_bounds__(256) void gat1_agg(const float2* __restrict__ featI,
                                                const float2* __restrict__ alpha,
                                                const float2* __restrict__ inv_s,
                                                const int* __restrict__ row_start,
                                                const int* __restrict__ csr_src,
                                                const float* __restrict__ b,
                                                float* __restrict__ h1, int N) {
  int wid = threadIdx.x >> 6;
  int lane = threadIdx.x & 63;
  int n = blockIdx.x * 4 + wid;
  if (n >= N) return;
  int beg = row_start[n], end = row_start[n + 1];
  float a0 = 0.f, a1 = 0.f;
  int i = beg;
  for (; i + 1 < end; i += 2) {
    int u0 = csr_src[i], u1 = csr_src[i + 1];
    float2 p0 = alpha[i], p1 = alpha[i + 1];
    float2 f0 = featI[(size_t)u0 * 64 + lane];
    float2 f1 = featI[(size_t)u1 * 64 + lane];
    a0 = fmaf(p0.x, f0.x, a0);
    a1 = fmaf(p0.y, f0.y, a1);
    a0 = fmaf(p1.x, f1.x, a0);
    a1 = fmaf(p1.y, f1.y, a1);
  }
  if (i < end) {
    float2 p = alpha[i];
    float2 f = featI[(size_t)csr_src[i] * 64 + lane];
    a0 = fmaf(p.x, f.x, a0);
    a1 = fmaf(p.y, f.y, a1);
  }
  float2 is = inv_s[n];
  float o0 = a0 * is.x + b[lane];
  float o1 = a1 * is.y + b[64 + lane];
  size_t base = (size_t)n * 128;
  h1[base + lane] = elu_f(o0);
  h1[base + 64 + lane] = elu_f(o1);
}

// ---------------- per-node attention logits (layer 2: 1 head x 47) --------
__global__ __launch_bounds__(256) void elr2_kernel(const float* __restrict__ feat,  // ld 48
                                                   const float* __restrict__ al,
                                                   const float* __restrict__ ar,
                                                   float* __restrict__ el,
                                                   float* __restrict__ er, int N) {
  int wid = threadIdx.x >> 6;
  int lane = threadIdx.x & 63;
  int n = blockIdx.x * 4 + wid;
  if (n >= N) return;
  float f = 0.f, a = 0.f, r = 0.f;
  if (lane < 47) {
    f = feat[(size_t)n * 48 + lane];
    a = al[lane];
    r = ar[lane];
  }
  float e = wave_sum(f * a);
  float rr = wave_sum(f * r);
  if (lane == 0) {
    el[n] = e;
    er[n] = rr;
  }
}

// ---------------- attn2: thread per node ----------------------------------
__global__ __launch_bounds__(256) void attn2_kernel(const float* __restrict__ el,
                                                    const float* __restrict__ er,
                                                    const int* __restrict__ row_start,
                                                    const int* __restrict__ csr_src,
                                                    float* __restrict__ alpha,
                                                    float* __restrict__ inv_s, int N) {
  int n = blockIdx.x * 256 + threadIdx.x;
  if (n >= N) return;
  int beg = row_start[n], end = row_start[n + 1];
  float r = er[n];
  float m = -INFINITY;
  for (int i = beg; i < end; ++i) {
    float e = el[csr_src[i]] + r;
    e = e > 0.f ? e : 0.2f * e;
    m = fmaxf(m, e);
  }
  float s = 0.f;
  for (int i = beg; i < end; ++i) {
    float e = el[csr_src[i]] + r;
    e = e > 0.f ? e : 0.2f * e;
    float p = __expf(e - m);
    s += p;
    alpha[i] = p;
  }
  inv_s[n] = 1.0f / fmaxf(s, 1e-9f);
}

// ---------------- fused GAT layer 2 aggregation -> d_out ------------------
__global__ __launch_bounds__(256) void gat2_agg(const float* __restrict__ feat,  // ld 48
                                                const float* __restrict__ alpha,
                                                const float* __restrict__ inv_s,
                                                const int* __restrict__ row_start,
                                                const int* __restrict__ csr_src,
                                                const float* __restrict__ b,
                                                float* __restrict__ out, int N) {
  int wid = threadIdx.x >> 6;
  int lane = threadIdx.x & 63;
  int n = blockIdx.x * 4 + wid;
  if (n >= N) return;
  int beg = row_start[n], end = row_start[n + 1];
  int lidx = lane < 47 ? lane : 0;
  float acc = 0.f;
  int i = beg;
  for (; i + 1 < end; i += 2) {
    int u0 = csr_src[i], u1 = csr_src[i + 1];
    float p0 = alpha[i], p1 = alpha[i + 1];
    acc = fmaf(p0, feat[(size_t)u0 * 48 + lidx], acc);
    acc = fmaf(p1, feat[(size_t)u1 * 48 + lidx], acc);
  }
  if (i < end) {
    acc = fmaf(alpha[i], feat[(size_t)csr_src[i] * 48 + lidx], acc);
  }
  if (lane < 47) {
    out[(size_t)n * 47 + lane] = acc * inv_s[n] + b[lane];
  }
}

// ---------------------------------------------------------------------------
extern "C" void kernel_launch(void* const* d_in, const int* in_sizes, int n_in,
                              void* d_out, int out_size, void* d_ws, size_t ws_size,
                              hipStream_t stream) {
  const float* x = (const float*)d_in[0];
  const int* src = (const int*)d_in[1];
  const int* dst = (const int*)d_in[2];
  const float* sage_w_self = (const float*)d_in[3];
  const float* sage_w_neigh = (const float*)d_in[4];
  const float* sage_b = (const float*)d_in[5];
  const float* gat1_w = (const float*)d_in[6];
  const float* gat1_al = (const float*)d_in[7];
  const float* gat1_ar = (const float*)d_in[8];
  const float* gat1_b = (const float*)d_in[9];
  const float* gat2_w = (const float*)d_in[10];
  const float* gat2_al = (const float*)d_in[11];
  const float* gat2_ar = (const float*)d_in[12];
  const float* gat2_b = (const float*)d_in[13];
  float* out = (float*)d_out;

  const int N = in_sizes[0] / 256;
  const int E = in_sizes[1];

  char* ws = (char*)d_ws;
  size_t off = 0;
  auto alloc = [&](size_t bytes) {
    size_t o = off;
    off += (bytes + 255) & ~(size_t)255;
    return o;
  };
  int* deg_i = (int*)(ws + alloc((size_t)N * 4));
  int* row_start = (int*)(ws + alloc((size_t)(N + 1) * 4));
  int* cursor = (int*)(ws + alloc((size_t)N * 4));
  int* csr_src = (int*)(ws + alloc((size_t)E * 4));
  float* bufA = (float*)(ws + alloc((size_t)N * 128 * 4));
  float* bufB = (float*)(ws + alloc((size_t)N * 128 * 4));
  float* bufC = (float*)(ws + alloc((size_t)N * 128 * 4));
  float2* el1 = (float2*)(ws + alloc((size_t)N * 8));
  float2* er1 = (float2*)(ws + alloc((size_t)N * 8));
  float* el2 = (float*)(ws + alloc((size_t)N * 4));
  float* er2 = (float*)(ws + alloc((size_t)N * 4));
  float2* inv_s1 = (float2*)(ws + alloc((size_t)N * 8));
  float* inv_s2 = (float*)(ws + alloc((size_t)N * 4));
  (void)ws_size;
  (void)n_in;
  (void)out_size;

  // buffer lifetime plan:
  float* z = bufA;                    // dead after sage_agg
  float* y = bufB;                    // (interleaved) dead after sage_agg
  float* h0 = bufC;                   // dead after feat1 gemm
  float* feat1 = bufA;                // (interleaved) dead after gat1_agg
  float2* alpha1 = (float2*)bufB;     // dead after gat1_agg
  float* h1 = bufC;                   // dead after feat2 gemm
  float* feat2 = bufA;                // ld 48
  float* alpha2 = bufB;

  hipMemsetAsync(deg_i, 0, (size_t)N * 4, stream);
  hipMemsetAsync(cursor, 0, (size_t)N * 4, stream);

  const int eb = (E + 255) / 256;
  const int nb4 = (N + 3) / 4;
  const int nb256 = (N + 255) / 256;
  const int gb = (N + 63) / 64;

  deg_kernel<<<eb, 256, 0, stream>>>(dst, deg_i, E);
  scan_kernel<<<1, 1024, 0, stream>>>(deg_i, row_start, N);
  scatter_kernel<<<eb, 256, 0, stream>>>(src, dst, row_start, cursor, csr_src, E);

  // layer 0: z = x @ W_self (standard), y = x @ W_neigh (interleaved)
  gemm_f32<64, 128, 16, 4, 8, 0><<<gb, 256, 0, stream>>>(x, 256, sage_w_self, 128, z, 128,
                                                         N, 128, 256);
  gemm_f32<64, 128, 16, 4, 8, 1><<<gb, 256, 0, stream>>>(x, 256, sage_w_neigh, 128, y, 128,
                                                         N, 128, 256);
  sage_agg<<<nb4, 256, 0, stream>>>(z, (const float2*)y, row_start, csr_src, sage_b, h0, N);

  // GAT layer 1 (feat1 interleaved)
  gemm_f32<64, 128, 16, 4, 8, 1><<<gb, 256, 0, stream>>>(h0, 128, gat1_w, 128, feat1, 128,
                                                         N, 128, 128);
  elr1_kernel<<<nb4, 256, 0, stream>>>((const float2*)feat1, gat1_al, gat1_ar, el1, er1, N);
  attn1_kernel<<<nb256, 256, 0, stream>>>(el1, er1, row_start, csr_src, alpha1, inv_s1, N);
  gat1_agg<<<nb4, 256, 0, stream>>>((const float2*)feat1, alpha1, inv_s1, row_start,
                                    csr_src, gat1_b, h1, N);

  // GAT layer 2
  gemm_f32<64, 64, 16, 4, 4, 0><<<gb, 256, 0, stream>>>(h1, 128, gat2_w, 47, feat2, 48,
                                                        N, 47, 128);
  elr2_kernel<<<nb4, 256, 0, stream>>>(feat2, gat2_al, gat2_ar, el2, er2, N);
  attn2_kernel<<<nb256, 256, 0, stream>>>(el2, er2, row_start, csr_src, alpha2, inv_s2, N);
  gat2_agg<<<nb4, 256, 0, stream>>>(feat2, alpha2, inv_s2, row_start, csr_src, gat2_b, out, N);
}